// Round 4
// baseline (1451.464 us; speedup 1.0000x reference)
//
#include <hip/hip_runtime.h>
#include <stdint.h>

// ---------------------------------------------------------------------------
// DeepSeek-V2 decoder layer, MI355X round 4.
// R3->R4: flatmm-style GEMM — A staged via swizzled global_load_lds (LDS,
// conflict-free), B fragments loaded DIRECTLY global->VGPR (bf16x8 typed
// loads), halving LDS read traffic (the R3 bottleneck: 256 clk LDS vs 77 clk
// MFMA per k32 per CU) and splitting operand feed across LDS + TA/L2 pipes.
// Everything else unchanged from R3 (passed, absmax 0.031).
// ---------------------------------------------------------------------------

#define S_   2048
#define D_   2048
#define H_   16
#define QL_  1536
#define KVL_ 512
#define DN_  128
#define DR_  64
#define DV_  128
#define I_   8192
#define SCALE_ 0.07216878364870323f   // (DN+DR)^-0.5

typedef __bf16 bf16x8 __attribute__((ext_vector_type(8)));
typedef float f32x4 __attribute__((ext_vector_type(4)));

__device__ __forceinline__ unsigned short f2bf(float f) {
  unsigned int u = __builtin_bit_cast(unsigned int, f);
  u += 0x7fffu + ((u >> 16) & 1u);           // RNE
  return (unsigned short)(u >> 16);
}
__device__ __forceinline__ float bf2f(unsigned short b) {
  unsigned int u = ((unsigned int)b) << 16;
  return __builtin_bit_cast(float, u);
}

__device__ __forceinline__ float block_sum256(float v) {
  __shared__ float red[4];
  #pragma unroll
  for (int o = 32; o; o >>= 1) v += __shfl_xor(v, o);
  __syncthreads();
  if ((threadIdx.x & 63) == 0) red[threadIdx.x >> 6] = v;
  __syncthreads();
  return red[0] + red[1] + red[2] + red[3];
}
__device__ __forceinline__ float block_max256(float v) {
  __shared__ float red[4];
  #pragma unroll
  for (int o = 32; o; o >>= 1) v = fmaxf(v, __shfl_xor(v, o));
  __syncthreads();
  if ((threadIdx.x & 63) == 0) red[threadIdx.x >> 6] = v;
  __syncthreads();
  return fmaxf(fmaxf(red[0], red[1]), fmaxf(red[2], red[3]));
}

__device__ __forceinline__ void gload_lds16(const void* g, void* l) {
  void* gn = const_cast<void*>(g);
  __builtin_amdgcn_global_load_lds(
      (__attribute__((address_space(1))) void*)gn,
      (__attribute__((address_space(3))) void*)l, 16, 0, 0);
}

// ---------------------------------------------------------------------------
// GEMM: C[M,N] = scale * A[M,K](bf16,lda) * Bt[N,K](bf16,ldb)^T (+R)
// 128x128 tile, BK=64, 256 threads (4 waves, 64x64 each, 4x4 mfma tiles).
// A: swizzled LDS staging (chunk c of row r at c^(r&7); global-source-side
// swizzle keeps global_load_lds dest contiguous). Fragment reads 2-way
// bank-aliased only (free, m136).
// B: DIRECT global->VGPR fragment loads (no LDS). Lane fr reads row
// n0+wn+j*16+fr at k+fq*8; wave covers 16 rows x 64B. Requires ldb%8==0.
// Rows may read past N (guarded in epilogue; source regions are in-bounds ws).
// OUT: 0=f32, 1=bf16, 2=silu-pair bf16 (even col=gate, odd=up; writes N/2).
// TRI: blockIdx.x linearizes lower-triangle of 16x16 grid. CK: K=min(K,m0+128).
// ---------------------------------------------------------------------------
template <int OUT, int ADD_RES, int TRI, int CK>
__global__ __launch_bounds__(256) void gemm_bt(
    const unsigned short* __restrict__ A, const unsigned short* __restrict__ Bt,
    void* __restrict__ C, const float* __restrict__ R, float scale,
    int M, int N, int K, int lda, int ldb, int ldc,
    long sA, long sB, long sC) {
  __shared__ unsigned short As[128 * 64];
  const int b = blockIdx.z;
  int bx = blockIdx.x, by = blockIdx.y;
  if (TRI) {
    const int t = blockIdx.x;
    int i = (int)((sqrtf(8.f * t + 1.f) - 1.f) * 0.5f);
    while ((i + 1) * (i + 2) / 2 <= t) ++i;
    while (i * (i + 1) / 2 > t) --i;
    by = i;
    bx = t - i * (i + 1) / 2;
  }
  const int m0 = by * 128, n0 = bx * 128;
  if (CK) K = min(K, m0 + 128);
  const int tid = threadIdx.x, w = tid >> 6, lane = tid & 63;
  const int wm = (w >> 1) * 64, wn = (w & 1) * 64;
  const int fr = lane & 15;      // m (A) / n (B) within 16-tile
  const int fq = lane >> 4;      // quad
  // A staging: lane covers row (base + lane/8), LDS chunk lane%8;
  // global source chunk = (lane%8) ^ (lane/8).
  const int sr = lane >> 3;
  const int sch = (lane & 7) ^ sr;
  const unsigned short* Ab = A + (long)b * sA;
  const unsigned short* Bb = Bt + (long)b * sB;
  long aOff[4];
  #pragma unroll
  for (int i = 0; i < 4; ++i)
    aOff[i] = (long)(m0 + w * 32 + i * 8 + sr) * lda + sch * 8;
  const unsigned short* bPtr[4];
  #pragma unroll
  for (int j = 0; j < 4; ++j)
    bPtr[j] = Bb + (long)(n0 + wn + j * 16 + fr) * ldb + fq * 8;
  // A fragment chunk indices (row&7 == fr&7)
  const int ca0 = fq ^ (fr & 7);
  const int ca1 = (4 + fq) ^ (fr & 7);

  f32x4 acc[4][4] = {};

  for (int k0 = 0; k0 < K; k0 += 64) {
    #pragma unroll
    for (int i = 0; i < 4; ++i)
      gload_lds16(Ab + aOff[i] + k0, As + (w * 32 + i * 8) * 64);
    bf16x8 b0[4];
    #pragma unroll
    for (int j = 0; j < 4; ++j)
      b0[j] = *(const bf16x8*)(bPtr[j] + k0);
    __syncthreads();                       // As + b0 ready (vmcnt drain)
    bf16x8 b1[4];
    #pragma unroll
    for (int j = 0; j < 4; ++j)            // issued now, consumed substep 1
      b1[j] = *(const bf16x8*)(bPtr[j] + k0 + 32);
    bf16x8 af[4];
    #pragma unroll
    for (int i = 0; i < 4; ++i)
      af[i] = *(const bf16x8*)(As + (wm + i * 16 + fr) * 64 + ca0 * 8);
    #pragma unroll
    for (int i = 0; i < 4; ++i)
      #pragma unroll
      for (int j = 0; j < 4; ++j)
        acc[i][j] = __builtin_amdgcn_mfma_f32_16x16x32_bf16(af[i], b0[j],
                                                            acc[i][j], 0, 0, 0);
    #pragma unroll
    for (int i = 0; i < 4; ++i)
      af[i] = *(const bf16x8*)(As + (wm + i * 16 + fr) * 64 + ca1 * 8);
    #pragma unroll
    for (int i = 0; i < 4; ++i)
      #pragma unroll
      for (int j = 0; j < 4; ++j)
        acc[i][j] = __builtin_amdgcn_mfma_f32_16x16x32_bf16(af[i], b1[j],
                                                            acc[i][j], 0, 0, 0);
    __syncthreads();                       // protect As before next staging
  }

  const long cb = (long)b * sC;
  #pragma unroll
  for (int i = 0; i < 4; ++i) {
    const int row0 = m0 + wm + i * 16 + fq * 4;
    #pragma unroll
    for (int j = 0; j < 4; ++j) {
      const int col = n0 + wn + j * 16 + fr;
      #pragma unroll
      for (int r = 0; r < 4; ++r) {
        float v = acc[i][j][r] * scale;
        if (OUT == 2) {
          const float o = __shfl_xor(v, 1);   // partner col (gate<->up)
          const float res = v / (1.f + __expf(-v)) * o;  // valid on even lanes
          if (((fr & 1) == 0) && col < N)
            ((unsigned short*)C)[cb + (long)(row0 + r) * ldc + (col >> 1)] =
                f2bf(res);
        } else {
          if (col < N) {
            const long idx = cb + (long)(row0 + r) * ldc + col;
            float vv = v;
            if (ADD_RES) vv += R[idx];
            if (OUT == 1) ((unsigned short*)C)[idx] = f2bf(vv);
            else          ((float*)C)[idx] = vv;
          }
        }
      }
    }
  }
}

// transpose + convert: in fp32 [R,C] -> out bf16 [C,R]; R,C multiples of 32.
__global__ void transpose_f2b(const float* __restrict__ in,
                              unsigned short* __restrict__ out, int Rr, int Cc,
                              long sIn, long sOut) {
  const int b = blockIdx.z;
  in += (long)b * sIn;
  out += (long)b * sOut;
  __shared__ float t[32][33];
  const int c0 = blockIdx.x * 32, r0 = blockIdx.y * 32;
  const int tx = threadIdx.x, ty = threadIdx.y;
  #pragma unroll
  for (int i = 0; i < 4; ++i)
    t[ty + i * 8][tx] = in[(long)(r0 + ty + i * 8) * Cc + c0 + tx];
  __syncthreads();
  #pragma unroll
  for (int i = 0; i < 4; ++i)
    out[(long)(c0 + ty + i * 8) * Rr + r0 + tx] = f2bf(t[tx][ty + i * 8]);
}

// interleaved transpose for gate_up: col c of [D,2I] -> row 2*(c%I)+(c/I).
__global__ void transpose_f2b_ilv(const float* __restrict__ in,
                                  unsigned short* __restrict__ out) {
  __shared__ float t[32][33];
  const int c0 = blockIdx.x * 32, r0 = blockIdx.y * 32;
  const int tx = threadIdx.x, ty = threadIdx.y;
  #pragma unroll
  for (int i = 0; i < 4; ++i)
    t[ty + i * 8][tx] = in[(long)(r0 + ty + i * 8) * (2 * I_) + c0 + tx];
  __syncthreads();
  #pragma unroll
  for (int i = 0; i < 4; ++i) {
    const int c = c0 + ty + i * 8;
    const int n = ((c & (I_ - 1)) << 1) | (c >> 13);
    out[(long)n * D_ + r0 + tx] = f2bf(t[tx][ty + i * 8]);
  }
}

// rmsnorm rows: y_bf16 = x * rsqrt(mean(x^2)+eps) * w
__global__ void rmsnorm_k(const float* __restrict__ x, const float* __restrict__ w,
                          unsigned short* __restrict__ y, int C) {
  const int row = blockIdx.x, tid = threadIdx.x;
  const float* xr = x + (long)row * C;
  float ss = 0.f;
  for (int c = tid; c < C; c += 256) { float v = xr[c]; ss += v * v; }
  ss = block_sum256(ss);
  const float rms = rsqrtf(ss / C + 1e-6f);
  for (int c = tid; c < C; c += 256)
    y[(long)row * C + c] = f2bf(xr[c] * rms * w[c]);
}

// q postprocess: split q (S,3072) into qnope bf16 (S,H*128) and roped pe into
// qf[h][s][512..575]
__global__ void q_post(const float* __restrict__ q, const float* __restrict__ cs,
                       const float* __restrict__ sn, unsigned short* __restrict__ qnope,
                       unsigned short* __restrict__ qf) {
  const int s = blockIdx.x, tid = threadIdx.x;
  const float* qr = q + (long)s * 3072;
  for (int c = tid; c < 3072; c += 256) {
    const int h = c / 192, d = c % 192;
    if (d < 128) {
      qnope[(long)s * 2048 + h * 128 + d] = f2bf(qr[c]);
    } else {
      const int j = d - 128;
      const float x = qr[c];
      const float rot = (j < 32) ? -qr[h * 192 + 128 + j + 32]
                                 :  qr[h * 192 + 128 + j - 32];
      const float v = x * cs[s * 64 + j] + rot * sn[s * 64 + j];
      qf[(long)h * (S_ * 576) + (long)s * 576 + 512 + j] = f2bf(v);
    }
  }
}

// kv postprocess: rmsnorm first 512 -> kf[:, :512] and klat^T; rope last 64.
__global__ void kv_post(const float* __restrict__ kv, const float* __restrict__ w,
                        const float* __restrict__ cs, const float* __restrict__ sn,
                        unsigned short* __restrict__ kf, unsigned short* __restrict__ klt) {
  const int s = blockIdx.x, tid = threadIdx.x;
  const float* kr = kv + (long)s * 576;
  float ss = 0.f;
  for (int c = tid; c < 512; c += 256) { float v = kr[c]; ss += v * v; }
  ss = block_sum256(ss);
  const float rms = rsqrtf(ss / 512.f + 1e-6f);
  for (int c = tid; c < 576; c += 256) {
    if (c < 512) {
      const float v = kr[c] * rms * w[c];
      const unsigned short bv = f2bf(v);
      kf[(long)s * 576 + c] = bv;
      klt[(long)c * S_ + s] = bv;
    } else {
      const int j = c - 512;
      const float x = kr[c];
      const float rot = (j < 32) ? -kr[512 + j + 32] : kr[512 + j - 32];
      kf[(long)s * 576 + c] = f2bf(x * cs[s * 64 + j] + rot * sn[s * 64 + j]);
    }
  }
}

// causal softmax IN-PLACE on bf16 scores. Row r: softmax over c<=r; zeros for
// c in (r, kmax), kmax = 128*ceil((r+1)/128) (cols the causal PV GEMM reads).
__global__ void softmax_causal_ip(unsigned short* __restrict__ sc, long hstride) {
  const int row = blockIdx.x, tid = threadIdx.x;
  unsigned short* sr = sc + (long)blockIdx.z * hstride + (long)row * S_;
  const int n = row + 1;
  const int kmax = ((row >> 7) + 1) << 7;
  float mx = -1e30f;
  for (int c = tid; c < n; c += 256) mx = fmaxf(mx, bf2f(sr[c]));
  mx = block_max256(mx);
  float e[8];
  float sum = 0.f;
  #pragma unroll
  for (int k = 0; k < 8; ++k) {
    const int c = tid + k * 256;
    if (c < n) { e[k] = __expf(bf2f(sr[c]) - mx); sum += e[k]; }
  }
  sum = block_sum256(sum);   // internal syncthreads: all reads of sr done
  const float inv = 1.f / sum;
  #pragma unroll
  for (int k = 0; k < 8; ++k) {
    const int c = tid + k * 256;
    if (c < n) sr[c] = f2bf(e[k] * inv);
    else if (c < kmax) sr[c] = 0;
  }
}

// ---------------------------------------------------------------------------
extern "C" void kernel_launch(void* const* d_in, const int* in_sizes, int n_in,
                              void* d_out, int out_size, void* d_ws, size_t ws_size,
                              hipStream_t stream) {
  const float* hs   = (const float*)d_in[0];
  const float* cs   = (const float*)d_in[1];
  const float* sn   = (const float*)d_in[2];
  const float* ln1  = (const float*)d_in[3];
  const float* qaw  = (const float*)d_in[4];
  const float* qaln = (const float*)d_in[5];
  const float* qbw  = (const float*)d_in[6];
  const float* kvaw = (const float*)d_in[7];
  const float* kvln = (const float*)d_in[8];
  const float* kcw  = (const float*)d_in[9];
  const float* vcw  = (const float*)d_in[10];
  const float* ow   = (const float*)d_in[11];
  const float* ln2  = (const float*)d_in[12];
  const float* guw  = (const float*)d_in[13];
  const float* dww  = (const float*)d_in[14];
  float* out = (float*)d_out;
  char* ws = (char*)d_ws;

  // ---- workspace layout (bytes); high-water 183697408 ----------------------
  // pre-attention (dead before scores are written)
  unsigned short* hbf   = (unsigned short*)(ws + 0);           // S*D bf16 8MB
  float*          qa    = (float*)(ws + 8388608);              // S*QL f32
  unsigned short* qan   = (unsigned short*)(ws + 20971520);    // S*QL bf16
  float*          q     = (float*)(ws + 27262976);             // S*3072 f32
  unsigned short* qnope = (unsigned short*)(ws + 52428800);    // S*2048 bf16 ends 60817408
  // attention
  unsigned short* sc    = (unsigned short*)(ws + 0);           // 8 heads S*S bf16 = 64MB
  unsigned short* qf    = (unsigned short*)(ws + 67108864);    // H*S*576 bf16 ends 104857600
  float*          kv    = (float*)(ws + 104857600);            // S*576 f32
  unsigned short* kf    = (unsigned short*)(ws + 109576192);   // S*576 bf16
  unsigned short* klt   = (unsigned short*)(ws + 111935488);   // 512*S bf16
  unsigned short* wt2   = (unsigned short*)(ws + 114032640);   // vc^T 2MB
  unsigned short* wt    = (unsigned short*)(ws + 116129792);   // weight scratch (<=67MB, ends 183697408)
  unsigned short* olat  = (unsigned short*)(ws + 116129792);   // H*S*512 bf16 (aliases wt; kc^T dead first,
                                                               // wt reused only after olat consumed)
  // post-attention
  unsigned short* obf   = (unsigned short*)(ws + 0);           // S*2048 bf16 8MB
  float*          hidden= (float*)(ws + 8388608);              // S*D f32 ends 25165824
  unsigned short* x2    = (unsigned short*)(ws + 25165824);    // S*D bf16 ends 33554432
  unsigned short* mlp   = (unsigned short*)(ws + 33554432);    // S*I bf16 ends 67108864

  const dim3 B256(256), Bt32(32, 8);

  // 1. h = rmsnorm(hidden_states, ln1)
  rmsnorm_k<<<S_, B256, 0, stream>>>(hs, ln1, hbf, D_);
  // 2-3. q_a = h @ q_a_w
  transpose_f2b<<<dim3(QL_/32, D_/32, 1), Bt32, 0, stream>>>(qaw, wt, D_, QL_, 0, 0);
  gemm_bt<0,0,0,0><<<dim3(QL_/128, S_/128, 1), B256, 0, stream>>>(
      hbf, wt, qa, nullptr, 1.f, S_, QL_, D_, D_, D_, QL_, 0, 0, 0);
  // 4. q_a_norm
  rmsnorm_k<<<S_, B256, 0, stream>>>(qa, qaln, qan, QL_);
  // 5-6. q = qan @ q_b_w
  transpose_f2b<<<dim3(3072/32, QL_/32, 1), Bt32, 0, stream>>>(qbw, wt, QL_, 3072, 0, 0);
  gemm_bt<0,0,0,0><<<dim3(3072/128, S_/128, 1), B256, 0, stream>>>(
      qan, wt, q, nullptr, 1.f, S_, 3072, QL_, QL_, QL_, 3072, 0, 0, 0);
  // 7. split q -> qnope bf16, rope(q_pe) -> qf[...,512:]
  q_post<<<S_, B256, 0, stream>>>(q, cs, sn, qnope, qf);
  // 8-9. kv = h @ kv_a_w
  transpose_f2b<<<dim3(576/32, D_/32, 1), Bt32, 0, stream>>>(kvaw, wt, D_, 576, 0, 0);
  gemm_bt<0,0,0,0><<<dim3(5, S_/128, 1), B256, 0, stream>>>(
      hbf, wt, kv, nullptr, 1.f, S_, 576, D_, D_, D_, 576, 0, 0, 0);
  // 10. kv_post: k_lat rmsnorm + transpose, k_pe rope
  kv_post<<<S_, B256, 0, stream>>>(kv, kvln, cs, sn, kf, klt);
  // 11-12. transpose kc_w (128x512 -> 512x128 per head) and vc_w (512x128 -> 128x512)
  transpose_f2b<<<dim3(512/32, 128/32, H_), Bt32, 0, stream>>>(kcw, wt, 128, 512, 65536, 65536);
  transpose_f2b<<<dim3(128/32, 512/32, H_), Bt32, 0, stream>>>(vcw, wt2, 512, 128, 65536, 65536);
  // 13. q_lat[h] = qnope[:,h,:] @ kc_w[h] -> qf[h][:, :512]
  gemm_bt<1,0,0,0><<<dim3(4, S_/128, H_), B256, 0, stream>>>(
      qnope, wt, qf, nullptr, 1.f, S_, 512, 128, 2048, 128, 576,
      128, 65536, (long)S_ * 576);
  // 14-19. attention, 2 groups of 8 heads
  for (int g = 0; g < 2; ++g) {
    const unsigned short* qfg = qf + (long)g * 8 * S_ * 576;
    gemm_bt<1,0,1,0><<<dim3(136, 1, 8), B256, 0, stream>>>(
        qfg, kf, sc, nullptr, SCALE_, S_, S_, 576, 576, 576, S_,
        (long)S_ * 576, 0, (long)S_ * S_);
    softmax_causal_ip<<<dim3(S_, 1, 8), B256, 0, stream>>>(sc, (long)S_ * S_);
    gemm_bt<1,0,0,1><<<dim3(4, 16, 8), B256, 0, stream>>>(
        sc, klt, olat + (long)g * 8 * S_ * 512, nullptr, 1.f,
        S_, 512, S_, S_, S_, 512, (long)S_ * S_, 0, (long)S_ * 512);
  }
  // 20. o[:, h*128:...] = o_lat[h] @ vc_w[h]
  gemm_bt<1,0,0,0><<<dim3(1, S_/128, H_), B256, 0, stream>>>(
      olat, wt2, obf, nullptr, 1.f, S_, 128, 512, 512, 512, 2048,
      (long)S_ * 512, 65536, 128);
  // 21-22. hidden = hs + o @ o_w   (residual fused into GEMM epilogue)
  transpose_f2b<<<dim3(D_/32, D_/32, 1), Bt32, 0, stream>>>(ow, wt, D_, D_, 0, 0);
  gemm_bt<0,1,0,0><<<dim3(D_/128, S_/128, 1), B256, 0, stream>>>(
      obf, wt, hidden, hs, 1.f, S_, D_, D_, D_, D_, D_, 0, 0, 0);
  // 23. x2 = rmsnorm(hidden, ln2)
  rmsnorm_k<<<S_, B256, 0, stream>>>(hidden, ln2, x2, D_);
  // 24-25. mlp = silu(x2@gate) * (x2@up)  (silu fused in epilogue, interleaved cols)
  transpose_f2b_ilv<<<dim3(2 * I_ / 32, D_/32, 1), Bt32, 0, stream>>>(guw, wt);
  gemm_bt<2,0,0,0><<<dim3(2 * I_ / 128, S_/128, 1), B256, 0, stream>>>(
      x2, wt, mlp, nullptr, 1.f, S_, 2 * I_, D_, D_, D_, I_, 0, 0, 0);
  // 26-27. out = hidden + mlp @ down_w
  transpose_f2b<<<dim3(D_/32, I_/32, 1), Bt32, 0, stream>>>(dww, wt, I_, D_, 0, 0);
  gemm_bt<0,1,0,0><<<dim3(D_/128, S_/128, 1), B256, 0, stream>>>(
      mlp, wt, out, hidden, 1.f, S_, D_, I_, I_, I_, D_, 0, 0, 0);
}

// Round 5
// 1196.434 us; speedup vs baseline: 1.2132x; 1.2132x over previous
//
#include <hip/hip_runtime.h>
#include <stdint.h>

// ---------------------------------------------------------------------------
// DeepSeek-V2 decoder layer, MI355X round 5.
// R4 failed (B-direct gathers). R5 = R3 GEMM structure (both operands via
// swizzled LDS, conflict-free) but wave tile 64x64 -> 128x64 (block 256x128,
// 4 waves 2x2): LDS bytes/FLOP 0.0457 -> 0.0343. R3 was LDS-BW-bound at
// MfmaUtil 36%; predict ~50%.
// ---------------------------------------------------------------------------

#define S_   2048
#define D_   2048
#define H_   16
#define QL_  1536
#define KVL_ 512
#define DN_  128
#define DR_  64
#define DV_  128
#define I_   8192
#define SCALE_ 0.07216878364870323f   // (DN+DR)^-0.5

typedef __bf16 bf16x8 __attribute__((ext_vector_type(8)));
typedef float f32x4 __attribute__((ext_vector_type(4)));

__device__ __forceinline__ unsigned short f2bf(float f) {
  unsigned int u = __builtin_bit_cast(unsigned int, f);
  u += 0x7fffu + ((u >> 16) & 1u);           // RNE
  return (unsigned short)(u >> 16);
}
__device__ __forceinline__ float bf2f(unsigned short b) {
  unsigned int u = ((unsigned int)b) << 16;
  return __builtin_bit_cast(float, u);
}

__device__ __forceinline__ float block_sum256(float v) {
  __shared__ float red[4];
  #pragma unroll
  for (int o = 32; o; o >>= 1) v += __shfl_xor(v, o);
  __syncthreads();
  if ((threadIdx.x & 63) == 0) red[threadIdx.x >> 6] = v;
  __syncthreads();
  return red[0] + red[1] + red[2] + red[3];
}
__device__ __forceinline__ float block_max256(float v) {
  __shared__ float red[4];
  #pragma unroll
  for (int o = 32; o; o >>= 1) v = fmaxf(v, __shfl_xor(v, o));
  __syncthreads();
  if ((threadIdx.x & 63) == 0) red[threadIdx.x >> 6] = v;
  __syncthreads();
  return fmaxf(fmaxf(red[0], red[1]), fmaxf(red[2], red[3]));
}

__device__ __forceinline__ void gload_lds16(const void* g, void* l) {
  void* gn = const_cast<void*>(g);
  __builtin_amdgcn_global_load_lds(
      (__attribute__((address_space(1))) void*)gn,
      (__attribute__((address_space(3))) void*)l, 16, 0, 0);
}

// ---------------------------------------------------------------------------
// GEMM: C[M,N] = scale * A[M,K](bf16,lda) * Bt[N,K](bf16,ldb)^T (+R)
// Block tile 256x128, BK=64, 256 threads = 4 waves (2x2), wave tile 128x64
// (8x4 mfma 16-tiles). Requires M%256==0, K%64==0, lda/ldb%8==0.
// LDS rows 128B; chunk c of row r stored at c^(r&7) (global-source swizzle;
// LDS dest contiguous as global_load_lds requires). ds_read_b128 fragment
// reads are 2-way bank-aliased only (free, m136).
// OUT: 0=f32, 1=bf16, 2=silu-pair bf16 (even col=gate, odd=up; writes N/2).
// TRI: blockIdx.x linearizes rows of lower-trapezoid {by in 0..M/256-1,
//      bx in 0..2*by+1}. CK: K=min(K,m0+256) (causal PV).
// ---------------------------------------------------------------------------
template <int OUT, int ADD_RES, int TRI, int CK>
__global__ __launch_bounds__(256, 2) void gemm_bt(
    const unsigned short* __restrict__ A, const unsigned short* __restrict__ Bt,
    void* __restrict__ C, const float* __restrict__ R, float scale,
    int M, int N, int K, int lda, int ldb, int ldc,
    long sA, long sB, long sC) {
  __shared__ unsigned short As[256 * 64];
  __shared__ unsigned short Bs[128 * 64];
  const int b = blockIdx.z;
  int bx = blockIdx.x, by = blockIdx.y;
  if (TRI) {
    const int t = blockIdx.x;
    int i = (int)((sqrtf(4.f * t + 1.f) - 1.f) * 0.5f);
    while ((i + 1) * (i + 2) <= t) ++i;
    while (i * (i + 1) > t) --i;
    by = i;
    bx = t - i * (i + 1);
  }
  const int m0 = by * 256, n0 = bx * 128;
  if (CK) K = min(K, m0 + 256);
  const int tid = threadIdx.x, w = tid >> 6, lane = tid & 63;
  const int wm = (w >> 1) * 128, wn = (w & 1) * 64;
  const int fr = lane & 15;      // m (A) / n (B) within 16-tile
  const int fq = lane >> 4;      // quad
  // staging: wave lane covers row group-base + lane/8, LDS chunk lane%8;
  // global source chunk = (lane%8) ^ (lane/8)   [row&7 == lane/8]
  const int sr = lane >> 3;
  const int sch = (lane & 7) ^ sr;
  const unsigned short* Ab = A + (long)b * sA;
  const unsigned short* Bb = Bt + (long)b * sB;
  long aOff[8], bOff[4];
  #pragma unroll
  for (int i = 0; i < 8; ++i)
    aOff[i] = (long)(m0 + w * 64 + i * 8 + sr) * lda + sch * 8;
  #pragma unroll
  for (int i = 0; i < 4; ++i)
    bOff[i] = (long)(n0 + w * 32 + i * 8 + sr) * ldb + sch * 8;
  // fragment chunk indices (row&7 == fr&7)
  const int ca0 = fq ^ (fr & 7);
  const int ca1 = (4 + fq) ^ (fr & 7);

  f32x4 acc[8][4] = {};

  for (int k0 = 0; k0 < K; k0 += 64) {
    #pragma unroll
    for (int i = 0; i < 8; ++i)
      gload_lds16(Ab + aOff[i] + k0, As + (w * 64 + i * 8) * 64);
    #pragma unroll
    for (int i = 0; i < 4; ++i)
      gload_lds16(Bb + bOff[i] + k0, Bs + (w * 32 + i * 8) * 64);
    __syncthreads();
    #pragma unroll
    for (int s = 0; s < 2; ++s) {
      const int cc = s ? ca1 : ca0;
      bf16x8 bf[4];
      #pragma unroll
      for (int j = 0; j < 4; ++j)
        bf[j] = *(const bf16x8*)(Bs + (wn + j * 16 + fr) * 64 + cc * 8);
      #pragma unroll
      for (int i = 0; i < 8; ++i) {
        const bf16x8 af = *(const bf16x8*)(As + (wm + i * 16 + fr) * 64 + cc * 8);
        #pragma unroll
        for (int j = 0; j < 4; ++j)
          acc[i][j] = __builtin_amdgcn_mfma_f32_16x16x32_bf16(af, bf[j],
                                                              acc[i][j], 0, 0, 0);
      }
    }
    __syncthreads();
  }

  const long cb = (long)b * sC;
  #pragma unroll
  for (int i = 0; i < 8; ++i) {
    const int row0 = m0 + wm + i * 16 + fq * 4;
    #pragma unroll
    for (int j = 0; j < 4; ++j) {
      const int col = n0 + wn + j * 16 + fr;
      #pragma unroll
      for (int r = 0; r < 4; ++r) {
        float v = acc[i][j][r] * scale;
        if (OUT == 2) {
          const float o = __shfl_xor(v, 1);   // partner col (gate<->up)
          const float res = v / (1.f + __expf(-v)) * o;  // valid on even lanes
          if (((fr & 1) == 0) && col < N)
            ((unsigned short*)C)[cb + (long)(row0 + r) * ldc + (col >> 1)] =
                f2bf(res);
        } else {
          if (col < N) {
            const long idx = cb + (long)(row0 + r) * ldc + col;
            float vv = v;
            if (ADD_RES) vv += R[idx];
            if (OUT == 1) ((unsigned short*)C)[idx] = f2bf(vv);
            else          ((float*)C)[idx] = vv;
          }
        }
      }
    }
  }
}

// transpose + convert: in fp32 [R,C] -> out bf16 [C,R]; R,C multiples of 32.
__global__ void transpose_f2b(const float* __restrict__ in,
                              unsigned short* __restrict__ out, int Rr, int Cc,
                              long sIn, long sOut) {
  const int b = blockIdx.z;
  in += (long)b * sIn;
  out += (long)b * sOut;
  __shared__ float t[32][33];
  const int c0 = blockIdx.x * 32, r0 = blockIdx.y * 32;
  const int tx = threadIdx.x, ty = threadIdx.y;
  #pragma unroll
  for (int i = 0; i < 4; ++i)
    t[ty + i * 8][tx] = in[(long)(r0 + ty + i * 8) * Cc + c0 + tx];
  __syncthreads();
  #pragma unroll
  for (int i = 0; i < 4; ++i)
    out[(long)(c0 + ty + i * 8) * Rr + r0 + tx] = f2bf(t[tx][ty + i * 8]);
}

// interleaved transpose for gate_up: col c of [D,2I] -> row 2*(c%I)+(c/I).
__global__ void transpose_f2b_ilv(const float* __restrict__ in,
                                  unsigned short* __restrict__ out) {
  __shared__ float t[32][33];
  const int c0 = blockIdx.x * 32, r0 = blockIdx.y * 32;
  const int tx = threadIdx.x, ty = threadIdx.y;
  #pragma unroll
  for (int i = 0; i < 4; ++i)
    t[ty + i * 8][tx] = in[(long)(r0 + ty + i * 8) * (2 * I_) + c0 + tx];
  __syncthreads();
  #pragma unroll
  for (int i = 0; i < 4; ++i) {
    const int c = c0 + ty + i * 8;
    const int n = ((c & (I_ - 1)) << 1) | (c >> 13);
    out[(long)n * D_ + r0 + tx] = f2bf(t[tx][ty + i * 8]);
  }
}

// rmsnorm rows: y_bf16 = x * rsqrt(mean(x^2)+eps) * w
__global__ void rmsnorm_k(const float* __restrict__ x, const float* __restrict__ w,
                          unsigned short* __restrict__ y, int C) {
  const int row = blockIdx.x, tid = threadIdx.x;
  const float* xr = x + (long)row * C;
  float ss = 0.f;
  for (int c = tid; c < C; c += 256) { float v = xr[c]; ss += v * v; }
  ss = block_sum256(ss);
  const float rms = rsqrtf(ss / C + 1e-6f);
  for (int c = tid; c < C; c += 256)
    y[(long)row * C + c] = f2bf(xr[c] * rms * w[c]);
}

// q postprocess: split q (S,3072) into qnope bf16 (S,H*128) and roped pe into
// qf[h][s][512..575]
__global__ void q_post(const float* __restrict__ q, const float* __restrict__ cs,
                       const float* __restrict__ sn, unsigned short* __restrict__ qnope,
                       unsigned short* __restrict__ qf) {
  const int s = blockIdx.x, tid = threadIdx.x;
  const float* qr = q + (long)s * 3072;
  for (int c = tid; c < 3072; c += 256) {
    const int h = c / 192, d = c % 192;
    if (d < 128) {
      qnope[(long)s * 2048 + h * 128 + d] = f2bf(qr[c]);
    } else {
      const int j = d - 128;
      const float x = qr[c];
      const float rot = (j < 32) ? -qr[h * 192 + 128 + j + 32]
                                 :  qr[h * 192 + 128 + j - 32];
      const float v = x * cs[s * 64 + j] + rot * sn[s * 64 + j];
      qf[(long)h * (S_ * 576) + (long)s * 576 + 512 + j] = f2bf(v);
    }
  }
}

// kv postprocess: rmsnorm first 512 -> kf[:, :512] and klat^T; rope last 64.
__global__ void kv_post(const float* __restrict__ kv, const float* __restrict__ w,
                        const float* __restrict__ cs, const float* __restrict__ sn,
                        unsigned short* __restrict__ kf, unsigned short* __restrict__ klt) {
  const int s = blockIdx.x, tid = threadIdx.x;
  const float* kr = kv + (long)s * 576;
  float ss = 0.f;
  for (int c = tid; c < 512; c += 256) { float v = kr[c]; ss += v * v; }
  ss = block_sum256(ss);
  const float rms = rsqrtf(ss / 512.f + 1e-6f);
  for (int c = tid; c < 576; c += 256) {
    if (c < 512) {
      const float v = kr[c] * rms * w[c];
      const unsigned short bv = f2bf(v);
      kf[(long)s * 576 + c] = bv;
      klt[(long)c * S_ + s] = bv;
    } else {
      const int j = c - 512;
      const float x = kr[c];
      const float rot = (j < 32) ? -kr[512 + j + 32] : kr[512 + j - 32];
      kf[(long)s * 576 + c] = f2bf(x * cs[s * 64 + j] + rot * sn[s * 64 + j]);
    }
  }
}

// causal softmax IN-PLACE on bf16 scores. Row r: softmax over c<=r; zeros for
// c in (r, kmax), kmax = 256*ceil((r+1)/256) (cols the causal PV GEMM reads).
__global__ void softmax_causal_ip(unsigned short* __restrict__ sc, long hstride) {
  const int row = blockIdx.x, tid = threadIdx.x;
  unsigned short* sr = sc + (long)blockIdx.z * hstride + (long)row * S_;
  const int n = row + 1;
  const int kmax = ((row >> 8) + 1) << 8;
  float mx = -1e30f;
  for (int c = tid; c < n; c += 256) mx = fmaxf(mx, bf2f(sr[c]));
  mx = block_max256(mx);
  float e[8];
  float sum = 0.f;
  #pragma unroll
  for (int k = 0; k < 8; ++k) {
    const int c = tid + k * 256;
    if (c < n) { e[k] = __expf(bf2f(sr[c]) - mx); sum += e[k]; }
  }
  sum = block_sum256(sum);   // internal syncthreads: all reads of sr done
  const float inv = 1.f / sum;
  #pragma unroll
  for (int k = 0; k < 8; ++k) {
    const int c = tid + k * 256;
    if (c < n) sr[c] = f2bf(e[k] * inv);
    else if (c < kmax) sr[c] = 0;
  }
}

// ---------------------------------------------------------------------------
extern "C" void kernel_launch(void* const* d_in, const int* in_sizes, int n_in,
                              void* d_out, int out_size, void* d_ws, size_t ws_size,
                              hipStream_t stream) {
  const float* hs   = (const float*)d_in[0];
  const float* cs   = (const float*)d_in[1];
  const float* sn   = (const float*)d_in[2];
  const float* ln1  = (const float*)d_in[3];
  const float* qaw  = (const float*)d_in[4];
  const float* qaln = (const float*)d_in[5];
  const float* qbw  = (const float*)d_in[6];
  const float* kvaw = (const float*)d_in[7];
  const float* kvln = (const float*)d_in[8];
  const float* kcw  = (const float*)d_in[9];
  const float* vcw  = (const float*)d_in[10];
  const float* ow   = (const float*)d_in[11];
  const float* ln2  = (const float*)d_in[12];
  const float* guw  = (const float*)d_in[13];
  const float* dww  = (const float*)d_in[14];
  float* out = (float*)d_out;
  char* ws = (char*)d_ws;

  // ---- workspace layout (bytes); high-water 183697408 ----------------------
  // pre-attention (dead before scores are written)
  unsigned short* hbf   = (unsigned short*)(ws + 0);           // S*D bf16 8MB
  float*          qa    = (float*)(ws + 8388608);              // S*QL f32
  unsigned short* qan   = (unsigned short*)(ws + 20971520);    // S*QL bf16
  float*          q     = (float*)(ws + 27262976);             // S*3072 f32
  unsigned short* qnope = (unsigned short*)(ws + 52428800);    // S*2048 bf16 ends 60817408
  // attention
  unsigned short* sc    = (unsigned short*)(ws + 0);           // 8 heads S*S bf16 = 64MB
  unsigned short* qf    = (unsigned short*)(ws + 67108864);    // H*S*576 bf16 ends 104857600
  float*          kv    = (float*)(ws + 104857600);            // S*576 f32
  unsigned short* kf    = (unsigned short*)(ws + 109576192);   // S*576 bf16
  unsigned short* klt   = (unsigned short*)(ws + 111935488);   // 512*S bf16
  unsigned short* wt2   = (unsigned short*)(ws + 114032640);   // vc^T 2MB
  unsigned short* wt    = (unsigned short*)(ws + 116129792);   // weight scratch (<=67MB, ends 183697408)
  unsigned short* olat  = (unsigned short*)(ws + 116129792);   // H*S*512 bf16 (aliases wt; kc^T dead first,
                                                               // wt reused only after olat consumed)
  // post-attention
  unsigned short* obf   = (unsigned short*)(ws + 0);           // S*2048 bf16 8MB
  float*          hidden= (float*)(ws + 8388608);              // S*D f32 ends 25165824
  unsigned short* x2    = (unsigned short*)(ws + 25165824);    // S*D bf16 ends 33554432
  unsigned short* mlp   = (unsigned short*)(ws + 33554432);    // S*I bf16 ends 67108864

  const dim3 B256(256), Bt32(32, 8);
  const int MY = S_ / 256;   // 8 M-blocks for all GEMMs (M=2048)

  // 1. h = rmsnorm(hidden_states, ln1)
  rmsnorm_k<<<S_, B256, 0, stream>>>(hs, ln1, hbf, D_);
  // 2-3. q_a = h @ q_a_w
  transpose_f2b<<<dim3(QL_/32, D_/32, 1), Bt32, 0, stream>>>(qaw, wt, D_, QL_, 0, 0);
  gemm_bt<0,0,0,0><<<dim3(QL_/128, MY, 1), B256, 0, stream>>>(
      hbf, wt, qa, nullptr, 1.f, S_, QL_, D_, D_, D_, QL_, 0, 0, 0);
  // 4. q_a_norm
  rmsnorm_k<<<S_, B256, 0, stream>>>(qa, qaln, qan, QL_);
  // 5-6. q = qan @ q_b_w
  transpose_f2b<<<dim3(3072/32, QL_/32, 1), Bt32, 0, stream>>>(qbw, wt, QL_, 3072, 0, 0);
  gemm_bt<0,0,0,0><<<dim3(3072/128, MY, 1), B256, 0, stream>>>(
      qan, wt, q, nullptr, 1.f, S_, 3072, QL_, QL_, QL_, 3072, 0, 0, 0);
  // 7. split q -> qnope bf16, rope(q_pe) -> qf[...,512:]
  q_post<<<S_, B256, 0, stream>>>(q, cs, sn, qnope, qf);
  // 8-9. kv = h @ kv_a_w
  transpose_f2b<<<dim3(576/32, D_/32, 1), Bt32, 0, stream>>>(kvaw, wt, D_, 576, 0, 0);
  gemm_bt<0,0,0,0><<<dim3(5, MY, 1), B256, 0, stream>>>(
      hbf, wt, kv, nullptr, 1.f, S_, 576, D_, D_, D_, 576, 0, 0, 0);
  // 10. kv_post: k_lat rmsnorm + transpose, k_pe rope
  kv_post<<<S_, B256, 0, stream>>>(kv, kvln, cs, sn, kf, klt);
  // 11-12. transpose kc_w (128x512 -> 512x128 per head) and vc_w (512x128 -> 128x512)
  transpose_f2b<<<dim3(512/32, 128/32, H_), Bt32, 0, stream>>>(kcw, wt, 128, 512, 65536, 65536);
  transpose_f2b<<<dim3(128/32, 512/32, H_), Bt32, 0, stream>>>(vcw, wt2, 512, 128, 65536, 65536);
  // 13. q_lat[h] = qnope[:,h,:] @ kc_w[h] -> qf[h][:, :512]
  gemm_bt<1,0,0,0><<<dim3(4, MY, H_), B256, 0, stream>>>(
      qnope, wt, qf, nullptr, 1.f, S_, 512, 128, 2048, 128, 576,
      128, 65536, (long)S_ * 576);
  // 14-19. attention, 2 groups of 8 heads
  for (int g = 0; g < 2; ++g) {
    const unsigned short* qfg = qf + (long)g * 8 * S_ * 576;
    // scores: causal trapezoid blocks (72 of 128), bf16 out, scaled
    gemm_bt<1,0,1,0><<<dim3(72, 1, 8), B256, 0, stream>>>(
        qfg, kf, sc, nullptr, SCALE_, S_, S_, 576, 576, 576, S_,
        (long)S_ * 576, 0, (long)S_ * S_);
    softmax_causal_ip<<<dim3(S_, 1, 8), B256, 0, stream>>>(sc, (long)S_ * S_);
    // o_lat = P @ k_lat : K truncated at m0+256 (causal)
    gemm_bt<1,0,0,1><<<dim3(4, MY, 8), B256, 0, stream>>>(
        sc, klt, olat + (long)g * 8 * S_ * 512, nullptr, 1.f,
        S_, 512, S_, S_, S_, 512, (long)S_ * S_, 0, (long)S_ * 512);
  }
  // 20. o[:, h*128:...] = o_lat[h] @ vc_w[h]
  gemm_bt<1,0,0,0><<<dim3(1, MY, H_), B256, 0, stream>>>(
      olat, wt2, obf, nullptr, 1.f, S_, 128, 512, 512, 512, 2048,
      (long)S_ * 512, 65536, 128);
  // 21-22. hidden = hs + o @ o_w   (residual fused into GEMM epilogue)
  transpose_f2b<<<dim3(D_/32, D_/32, 1), Bt32, 0, stream>>>(ow, wt, D_, D_, 0, 0);
  gemm_bt<0,1,0,0><<<dim3(D_/128, MY, 1), B256, 0, stream>>>(
      obf, wt, hidden, hs, 1.f, S_, D_, D_, D_, D_, D_, 0, 0, 0);
  // 23. x2 = rmsnorm(hidden, ln2)
  rmsnorm_k<<<S_, B256, 0, stream>>>(hidden, ln2, x2, D_);
  // 24-25. mlp = silu(x2@gate) * (x2@up)  (silu fused in epilogue, interleaved cols)
  transpose_f2b_ilv<<<dim3(2 * I_ / 32, D_/32, 1), Bt32, 0, stream>>>(guw, wt);
  gemm_bt<2,0,0,0><<<dim3(2 * I_ / 128, MY, 1), B256, 0, stream>>>(
      x2, wt, mlp, nullptr, 1.f, S_, 2 * I_, D_, D_, D_, I_, 0, 0, 0);
  // 26-27. out = hidden + mlp @ down_w
  transpose_f2b<<<dim3(D_/32, I_/32, 1), Bt32, 0, stream>>>(dww, wt, I_, D_, 0, 0);
  gemm_bt<0,1,0,0><<<dim3(D_/128, MY, 1), B256, 0, stream>>>(
      mlp, wt, out, hidden, 1.f, S_, D_, I_, I_, I_, D_, 0, 0, 0);
}